// Round 3
// baseline (388.877 us; speedup 1.0000x reference)
//
#include <hip/hip_runtime.h>
#include <cstdint>
#include <cmath>

#define BATCH 65536
#define NREAL 246
#define NPAD  256
#define K1    784
#define K1PAD 832
#define BINS  100
#define ALPHA 0.1f
#define RB    64
#define NBLK  (BATCH/RB)     // 1024

typedef __bf16 bf16x8 __attribute__((ext_vector_type(8)));
typedef __bf16 bf16x4 __attribute__((ext_vector_type(4)));
typedef float  f32x4  __attribute__((ext_vector_type(4)));

// LDS layout (bytes)
#define OFF_HS     0         // 64 rows * 512B = 32768
#define OFF_STAGE  32768     // L1 stage dbuf 2*8192 (union with hist)
#define OFF_HIST   32768     // 8 waves * 800 bins * 4B = 25600
#define OFF_MN     58368     // 64 rows * 4 colwaves * 4B = 1024
#define OFF_MX     59392     // 1024
#define OFF_LUT    60416     // 256 * 4B
#define OFF_WENT   61440     // 8 waves * 6 layers * 4B = 192
#define LDS_TOTAL  61696

// ---------------- weight pad/convert: fp32 -> bf16, zero-padded ----------------
__global__ __launch_bounds__(256)
void pad_weights(const float* __restrict__ W1, const float* __restrict__ W2,
                 const float* __restrict__ W3, const float* __restrict__ W4,
                 const float* __restrict__ W5, const float* __restrict__ W6,
                 const float* __restrict__ W7,
                 __bf16* __restrict__ W1p, __bf16* __restrict__ Wp,
                 __bf16* __restrict__ W7p)
{
    int tid = blockIdx.x * 256 + threadIdx.x;
    const int n1 = NPAD * K1PAD;        // 212992
    const int n2 = 5 * NPAD * NPAD;     // 327680
    if (tid < n1) {
        int row = tid / K1PAD;
        int k   = tid - row * K1PAD;
        W1p[tid] = (__bf16)((row < NREAL && k < K1) ? W1[row * K1 + k] : 0.0f);
    } else if (tid < n1 + n2) {
        int t = tid - n1;
        int wsel = t >> 16;
        int idx  = t & 65535;
        int row  = idx >> 8, k = idx & 255;
        const float* W = (wsel == 0) ? W2 : (wsel == 1) ? W3 : (wsel == 2) ? W4
                        : (wsel == 3) ? W5 : W6;
        Wp[t] = (__bf16)((row < NREAL && k < NREAL) ? W[row * NREAL + k] : 0.0f);
    } else if (tid < n1 + n2 + 16 * NPAD) {
        int t = tid - n1 - n2;
        int row = t >> 8, k = t & 255;
        W7p[t] = (__bf16)((row < 10 && k < NREAL) ? W7[row * NREAL + k] : 0.0f);
    }
}

// ---------------- megakernel ----------------
__global__ __launch_bounds__(512, 4)
void mega(const float* __restrict__ x,
          const __bf16* __restrict__ W1p,
          const __bf16* __restrict__ Wp,
          const __bf16* __restrict__ W7p,
          const float* __restrict__ b1, const float* __restrict__ b2,
          const float* __restrict__ b3, const float* __restrict__ b4,
          const float* __restrict__ b5, const float* __restrict__ b6,
          const float* __restrict__ b7,
          float* __restrict__ out, float* __restrict__ partial)
{
    __shared__ char smem[LDS_TOTAL];
    char*  Hb    = smem + OFF_HS;
    float* rowmn = (float*)(smem + OFF_MN);
    float* rowmx = (float*)(smem + OFF_MX);
    float* lut   = (float*)(smem + OFF_LUT);
    float* went  = (float*)(smem + OFF_WENT);

    const int tid = threadIdx.x;
    const int w = tid >> 6, l = tid & 63;
    const int lane16 = l & 15, lane4 = l >> 4;
    const int wr = (w >> 2) * 32;        // 2 row-wave groups
    const int wc = (w & 3) * 64;         // 4 col-wave groups
    const int m0 = blockIdx.x * RB;

    // c*ln(c) LUT
    if (tid > 0 && tid < 247) lut[tid] = (float)tid * logf((float)tid);
    if (tid == 0) lut[0] = 0.0f;

    f32x4 acc[2][4];
#pragma unroll
    for (int i = 0; i < 2; ++i)
#pragma unroll
        for (int j = 0; j < 4; ++j) acc[i][j] = f32x4{0.f, 0.f, 0.f, 0.f};

    // ---------- epilogue: bias + leaky + Hs write (swizzled) + per-row min/max ----------
    auto epilogue = [&](const float* bias) {
        float bv[4];
#pragma unroll
        for (int j = 0; j < 4; ++j) {
            int col = wc + j * 16 + lane16;
            bv[j] = (col < NREAL) ? bias[col] : 0.0f;
        }
#pragma unroll
        for (int i = 0; i < 2; ++i) {
#pragma unroll
            for (int rr = 0; rr < 4; ++rr) {
                int row = wr + i * 16 + lane4 * 4 + rr;
                int swz = (row & 7) << 4;
                float mn = 1e30f, mx = -1e30f;
#pragma unroll
                for (int j = 0; j < 4; ++j) {
                    int col = wc + j * 16 + lane16;
                    bool cv = col < NREAL;
                    float v = acc[i][j][rr] + bv[j];
                    v = v > 0.0f ? v : ALPHA * v;
                    *(__bf16*)(Hb + row * 512 + ((col * 2) ^ swz)) = cv ? (__bf16)v : (__bf16)0.0f;
                    mn = fminf(mn, cv ? v : 1e30f);
                    mx = fmaxf(mx, cv ? v : -1e30f);
                }
#pragma unroll
                for (int off = 1; off < 16; off <<= 1) {
                    mn = fminf(mn, __shfl_xor(mn, off, 64));
                    mx = fmaxf(mx, __shfl_xor(mx, off, 64));
                }
                if (lane16 == 0) {
                    rowmn[row * 4 + (w & 3)] = mn;
                    rowmx[row * 4 + (w & 3)] = mx;
                }
            }
        }
    };

    // ---------- entropy: wave w handles rows w*8 .. w*8+7, all in one flat pass ----------
    auto entropy = [&](int li) {
        int* histW = (int*)(smem + OFF_HIST) + w * 800;
        // lane l combines row-l min/max across the 4 col-waves
        f32x4 m4 = *(const f32x4*)(rowmn + l * 4);
        f32x4 x4 = *(const f32x4*)(rowmx + l * 4);
        float mnl = fminf(fminf(m4[0], m4[1]), fminf(m4[2], m4[3]));
        float mxl = fmaxf(fmaxf(x4[0], x4[1]), fmaxf(x4[2], x4[3]));
        float rgl = mxl - mnl;
        float rsl = (rgl > 0.0f) ? 100.0f / rgl : 0.0f;
        // zero this wave's 800 bins
#pragma unroll
        for (int t = 0; t < 13; ++t) { int b = t * 64 + l; if (b < 800) histW[b] = 0; }
        asm volatile("s_waitcnt lgkmcnt(0)" ::: "memory");
        // fill: no cross-lane deps (min/max broadcast via readlane)
        const int c0 = l * 4;
#pragma unroll
        for (int rr = 0; rr < 8; ++rr) {
            int row = w * 8 + rr;
            float rm = __shfl(mnl, row, 64);
            float rs = __shfl(rsl, row, 64);
            bf16x4 hv = *(const bf16x4*)(Hb + row * 512 + ((c0 * 2) ^ ((row & 7) << 4)));
#pragma unroll
            for (int e = 0; e < 4; ++e) {
                if (c0 + e < NREAL) {
                    int idx = (int)floorf(((float)hv[e] - rm) * rs);
                    idx = idx < 0 ? 0 : (idx > BINS - 1 ? BINS - 1 : idx);
                    atomicAdd(&histW[rr * 100 + idx], 1);
                }
            }
        }
        asm volatile("s_waitcnt lgkmcnt(0)" ::: "memory");
        // vectorized sum of c*ln(c) over the wave's 8 histograms
        float S = 0.0f;
        const int rbase = (l >> 3) * 100, tb = (l & 7) * 13;
#pragma unroll
        for (int t = 0; t < 13; ++t) {
            int b = tb + t;
            if (b < 100) S += lut[histW[rbase + b]];
        }
#pragma unroll
        for (int off = 1; off < 64; off <<= 1) S += __shfl_xor(S, off, 64);
        if (l == 0) went[w * 6 + li] = 8.0f * logf(246.0f) - S * (1.0f / 246.0f);
    };

    // ================= layer 1: K=784 streamed from HBM via reg-relay stage =================
    {
        const int srow = tid >> 3;        // 0..63
        const int skc  = (tid & 7) * 8;   // k offset within 64
        float4 xr0, xr1;
        auto issueX = [&](int kt) {
            int k0 = kt * 64 + skc;
            if (k0 < K1) {                // chunks of 8 fully valid (784 % 8 == 0)
                const float* gx = x + (size_t)(m0 + srow) * K1 + k0;
                xr0 = *(const float4*)gx;
                xr1 = *(const float4*)(gx + 4);
            } else {
                xr0 = float4{0.f,0.f,0.f,0.f};
                xr1 = float4{0.f,0.f,0.f,0.f};
            }
        };
        auto writeX = [&](int buf) {
            bf16x8 h;
            h[0]=(__bf16)xr0.x; h[1]=(__bf16)xr0.y; h[2]=(__bf16)xr0.z; h[3]=(__bf16)xr0.w;
            h[4]=(__bf16)xr1.x; h[5]=(__bf16)xr1.y; h[6]=(__bf16)xr1.z; h[7]=(__bf16)xr1.w;
            char* st = smem + OFF_STAGE + buf * 8192;
            *(bf16x8*)(st + srow * 128 + ((skc * 2) ^ ((srow & 7) << 4))) = h;
        };
        auto l1step = [&](int kt, int buf) {
            const char* st = smem + OFF_STAGE + buf * 8192;
#pragma unroll
            for (int kk = 0; kk < 2; ++kk) {
                bf16x8 bfr[4];
#pragma unroll
                for (int j = 0; j < 4; ++j)
                    bfr[j] = *(const bf16x8*)(W1p + (size_t)(wc + j * 16 + lane16) * K1PAD
                                              + kt * 64 + kk * 32 + lane4 * 8);
                bf16x8 af[2];
#pragma unroll
                for (int i = 0; i < 2; ++i) {
                    int row = wr + i * 16 + lane16;
                    af[i] = *(const bf16x8*)(st + row * 128 + ((kk * 64 + lane4 * 16) ^ ((row & 7) << 4)));
                }
#pragma unroll
                for (int i = 0; i < 2; ++i)
#pragma unroll
                    for (int j = 0; j < 4; ++j)
                        acc[i][j] = __builtin_amdgcn_mfma_f32_16x16x32_bf16(af[i], bfr[j], acc[i][j], 0, 0, 0);
            }
        };

        issueX(0);
        writeX(0);
        issueX(1);
        for (int kt = 0; kt < 13; ++kt) {
            __syncthreads();
            if (kt < 12) {
                writeX((kt + 1) & 1);
                if (kt < 11) issueX(kt + 2);
            }
            l1step(kt, kt & 1);
        }
    }
    epilogue(b1);          // writes Hs/minmax; L1 stage region no longer read after barrier below
    __syncthreads();
    entropy(0);

    // ================= layers 2..6: A from Hs (LDS), B from L2 =================
    const float* bsel[5] = {b2, b3, b4, b5, b6};
    for (int li = 0; li < 5; ++li) {
        const __bf16* Bp = Wp + (size_t)li * (NPAD * NPAD);
#pragma unroll
        for (int i = 0; i < 2; ++i)
#pragma unroll
            for (int j = 0; j < 4; ++j) acc[i][j] = f32x4{0.f, 0.f, 0.f, 0.f};
#pragma unroll
        for (int kt = 0; kt < 4; ++kt) {
#pragma unroll
            for (int kk = 0; kk < 2; ++kk) {
                bf16x8 bfr[4];
#pragma unroll
                for (int j = 0; j < 4; ++j)
                    bfr[j] = *(const bf16x8*)(Bp + (size_t)(wc + j * 16 + lane16) * NPAD
                                              + kt * 64 + kk * 32 + lane4 * 8);
                bf16x8 af[2];
#pragma unroll
                for (int i = 0; i < 2; ++i) {
                    int row = wr + i * 16 + lane16;
                    af[i] = *(const bf16x8*)(Hb + row * 512
                              + ((kt * 128 + kk * 64 + lane4 * 16) ^ ((row & 7) << 4)));
                }
#pragma unroll
                for (int i = 0; i < 2; ++i)
#pragma unroll
                    for (int j = 0; j < 4; ++j)
                        acc[i][j] = __builtin_amdgcn_mfma_f32_16x16x32_bf16(af[i], bfr[j], acc[i][j], 0, 0, 0);
            }
        }
        __syncthreads();       // all waves done reading Hs
        epilogue(bsel[li]);
        __syncthreads();       // new Hs + minmax visible
        entropy(li + 1);
    }

    // ================= head: waves 0..3, one 16-row MFMA strip each =================
    if (w < 4) {
        f32x4 hacc = f32x4{0.f, 0.f, 0.f, 0.f};
        int row = w * 16 + lane16;
#pragma unroll
        for (int kt = 0; kt < 8; ++kt) {
            bf16x8 af = *(const bf16x8*)(Hb + row * 512 + ((kt * 64 + lane4 * 16) ^ ((row & 7) << 4)));
            bf16x8 bf = *(const bf16x8*)(W7p + (size_t)lane16 * NPAD + kt * 32 + lane4 * 8);
            hacc = __builtin_amdgcn_mfma_f32_16x16x32_bf16(af, bf, hacc, 0, 0, 0);
        }
        float bv = (lane16 < 10) ? b7[lane16] : 0.0f;
#pragma unroll
        for (int r = 0; r < 4; ++r) {
            float lg = fmaxf(hacc[r] + bv, 0.0f);
            float vm = (lane16 < 10) ? lg : -1e30f;
#pragma unroll
            for (int off = 8; off; off >>= 1) vm = fmaxf(vm, __shfl_xor(vm, off, 64));
            float ex = (lane16 < 10) ? expf(lg - vm) : 0.0f;
#pragma unroll
            for (int off = 8; off; off >>= 1) ex += __shfl_xor(ex, off, 64);
            float ls = vm + logf(ex);
            if (lane16 < 10) {
                int grow = m0 + w * 16 + lane4 * 4 + r;
                out[(size_t)grow * 10 + lane16] = lg - ls;
            }
        }
    }

    __syncthreads();
    if (tid < 6) {
        float s = 0.0f;
#pragma unroll
        for (int q = 0; q < 8; ++q) s += went[q * 6 + tid];
        partial[tid * NBLK + blockIdx.x] = s;
    }
}

// ---------------- final entropy mean (deterministic fixed-order) ----------------
__global__ __launch_bounds__(256)
void reduce_kernel(const float* __restrict__ partial, float* __restrict__ out)
{
    __shared__ float s[256];
    const int li = blockIdx.x, tid = threadIdx.x;
    float a = 0.0f;
    for (int i = tid; i < NBLK; i += 256) a += partial[li * NBLK + i];
    s[tid] = a;
    __syncthreads();
    for (int st = 128; st; st >>= 1) {
        if (tid < st) s[tid] += s[tid + st];
        __syncthreads();
    }
    if (tid == 0)
        out[(size_t)BATCH * 10 + li] = s[0] / (float)BATCH + logf((float)BINS);
}

// ---------------- launch ----------------
extern "C" void kernel_launch(void* const* d_in, const int* in_sizes, int n_in,
                              void* d_out, int out_size, void* d_ws, size_t ws_size,
                              hipStream_t stream)
{
    (void)in_sizes; (void)n_in; (void)out_size; (void)ws_size;

    const float* x  = (const float*)d_in[0];
    const float* W1 = (const float*)d_in[1];
    const float* b1 = (const float*)d_in[2];
    const float* W2 = (const float*)d_in[3];
    const float* b2 = (const float*)d_in[4];
    const float* W3 = (const float*)d_in[5];
    const float* b3 = (const float*)d_in[6];
    const float* W4 = (const float*)d_in[7];
    const float* b4 = (const float*)d_in[8];
    const float* W5 = (const float*)d_in[9];
    const float* b5 = (const float*)d_in[10];
    const float* W6 = (const float*)d_in[11];
    const float* b6 = (const float*)d_in[12];
    const float* W7 = (const float*)d_in[13];
    const float* b7 = (const float*)d_in[14];

    char* ws = (char*)d_ws;
    // ws layout (bytes):
    //   0       : W1p  256*832 bf16   = 425984
    //   425984  : Wp   5*256*256 bf16 = 655360
    //   1081344 : W7p  16*256 bf16    = 8192
    //   1089536 : partial 6*1024 f32  = 24576
    __bf16* W1p = (__bf16*)(ws);
    __bf16* Wp  = (__bf16*)(ws + 425984);
    __bf16* W7p = (__bf16*)(ws + 1081344);
    float*  partial = (float*)(ws + 1089536);
    float*  out = (float*)d_out;

    pad_weights<<<2128, 256, 0, stream>>>(W1, W2, W3, W4, W5, W6, W7, W1p, Wp, W7p);
    mega<<<NBLK, 512, 0, stream>>>(x, W1p, Wp, W7p, b1, b2, b3, b4, b5, b6, b7, out, partial);
    reduce_kernel<<<6, 256, 0, stream>>>(partial, out);
}